// Round 4
// baseline (383.561 us; speedup 1.0000x reference)
//
#include <hip/hip_runtime.h>
#include <stdint.h>

#define KBOX 1024
#define EPSF 1e-4f
#define SLACK 3e-5f
#define FILL_BLOCKS 2048  // 2048*256 float4 = 2*K*K floats

// ws layout (bytes):
//   0      : int flag  (1 = bool byte layout, 0 = int32 layout)
//   16     : back [K][12] f32  (48 KB)  rows of inverse affine (3x4)
//   49168  : hp   [K][24] f32  (96 KB)  posed corners xyz
//   147472 : wmn  [K][4] f32   (16 KB)  world AABB min (slack-expanded)
//   163856 : wmx  [K][4] f32   (16 KB)  world AABB max
//   180240 : bne  [K][4] f32   (16 KB)  bb_min + EPS
//   196624 : bxe  [K][4] f32   (16 KB)  bb_max - EPS
//   213008 : pub  [K] u64      (8 KB)   decoupled-lookback state (cleared by k_prep)
#define BACK_OFF 16
#define HP_OFF   49168
#define WMN_OFF  147472
#define WMX_OFF  163856
#define BNE_OFF  180240
#define BXE_OFF  196624
#define PUB_OFF  213008

__global__ void k_prep(const float* __restrict__ bbmin, const float* __restrict__ bbmax,
                       const float* __restrict__ A, const uint8_t* __restrict__ dis,
                       int* __restrict__ flag,
                       float* __restrict__ back, float* __restrict__ hp,
                       float* __restrict__ out_hposed,
                       float* __restrict__ wmn, float* __restrict__ wmx,
                       float* __restrict__ bne, float* __restrict__ bxe,
                       uint64_t* __restrict__ pub, float4* __restrict__ fillp) {
    int bid = blockIdx.x;
    int t = threadIdx.x;
    if (bid < FILL_BLOCKS) {
        fillp[bid * 256 + t] = make_float4(-1.f, -1.f, -1.f, -1.f);
        return;
    }
    if (bid < FILL_BLOCKS + 4) {
        int k = (bid - FILL_BLOCKS) * 256 + t;
        const float* a = A + (size_t)k * 16;
        float r[3][4];
#pragma unroll
        for (int i = 0; i < 3; ++i)
#pragma unroll
            for (int j = 0; j < 4; ++j) r[i][j] = a[i * 4 + j];

        // double-precision analytic inverse of the 3x3 block
        double m00 = r[0][0], m01 = r[0][1], m02 = r[0][2];
        double m10 = r[1][0], m11 = r[1][1], m12 = r[1][2];
        double m20 = r[2][0], m21 = r[2][1], m22 = r[2][2];
        double c00 = m11 * m22 - m12 * m21;
        double c01 = m12 * m20 - m10 * m22;
        double c02 = m10 * m21 - m11 * m20;
        double det = m00 * c00 + m01 * c01 + m02 * c02;
        double id = 1.0 / det;
        double inv[3][3];
        inv[0][0] = c00 * id;
        inv[0][1] = (m02 * m21 - m01 * m22) * id;
        inv[0][2] = (m01 * m12 - m02 * m11) * id;
        inv[1][0] = c01 * id;
        inv[1][1] = (m00 * m22 - m02 * m20) * id;
        inv[1][2] = (m02 * m10 - m00 * m12) * id;
        inv[2][0] = c02 * id;
        inv[2][1] = (m01 * m20 - m00 * m21) * id;
        inv[2][2] = (m00 * m11 - m01 * m10) * id;
        double tx = r[0][3], ty = r[1][3], tz = r[2][3];
#pragma unroll
        for (int i = 0; i < 3; ++i) {
            back[(size_t)k * 12 + i * 4 + 0] = (float)inv[i][0];
            back[(size_t)k * 12 + i * 4 + 1] = (float)inv[i][1];
            back[(size_t)k * 12 + i * 4 + 2] = (float)inv[i][2];
            back[(size_t)k * 12 + i * 4 + 3] =
                (float)(-(inv[i][0] * tx + inv[i][1] * ty + inv[i][2] * tz));
        }

        float bmn[3], bmx[3];
#pragma unroll
        for (int i = 0; i < 3; ++i) { bmn[i] = bbmin[k * 3 + i]; bmx[i] = bbmax[k * 3 + i]; }
        *(float4*)(bne + (size_t)k * 4) =
            make_float4(bmn[0] + EPSF, bmn[1] + EPSF, bmn[2] + EPSF, 0.f);
        *(float4*)(bxe + (size_t)k * 4) =
            make_float4(bmx[0] - EPSF, bmx[1] - EPSF, bmx[2] - EPSF, 0.f);

        float wn[3] = {1e30f, 1e30f, 1e30f}, wx[3] = {-1e30f, -1e30f, -1e30f};
#pragma unroll
        for (int c = 0; c < 8; ++c) {
            float cx = ((c >> 2) & 1) ? bmx[0] : bmn[0];
            float cy = ((c >> 1) & 1) ? bmx[1] : bmn[1];
            float cz = (c & 1) ? bmx[2] : bmn[2];
#pragma unroll
            for (int i = 0; i < 3; ++i) {
                float p = r[i][0] * cx + r[i][1] * cy + r[i][2] * cz + r[i][3];
                hp[(size_t)k * 24 + c * 3 + i] = p;
                out_hposed[(size_t)k * 24 + c * 3 + i] = p;
                wn[i] = fminf(wn[i], p);
                wx[i] = fmaxf(wx[i], p);
            }
        }
        *(float4*)(wmn + (size_t)k * 4) =
            make_float4(wn[0] - SLACK, wn[1] - SLACK, wn[2] - SLACK, 0.f);
        *(float4*)(wmx + (size_t)k * 4) =
            make_float4(wx[0] + SLACK, wx[1] + SLACK, wx[2] + SLACK, 0.f);
        return;
    }
    // last block: clear lookback state (every replay) + detect dis layout
    for (int i = t; i < KBOX; i += 256) pub[i] = 0ull;
    __shared__ int s;
    if (t == 0) s = 0;
    __syncthreads();
    int acc = 0;
    for (int i = t; i < 4096; i += 256) {
        if ((i & 3) != 0 && dis[i] != 0) acc = 1;
    }
    if (acc) atomicOr(&s, 1);
    __syncthreads();
    if (t == 0) *flag = s;
}

__global__ void k_inside_compact(const float* __restrict__ back, const float* __restrict__ hp,
                                 const float* __restrict__ wmn, const float* __restrict__ wmx,
                                 const float* __restrict__ bne, const float* __restrict__ bxe,
                                 const uint8_t* __restrict__ disB, const int* __restrict__ flag,
                                 uint64_t* __restrict__ pub, float* __restrict__ out) {
    int k = blockIdx.x;
    __shared__ float bk[12], hk[24], bnek[3], bxek[3], wmnk[3], wmxk[3];
    __shared__ uint64_t words[16];
    __shared__ uint32_t cntS;
    int t = threadIdx.x;
    if (t < 16) words[t] = 0ull;
    if (t < 12) bk[t] = back[(size_t)k * 12 + t];
    if (t < 24) hk[t] = hp[(size_t)k * 24 + t];
    if (t < 3) {
        bnek[t] = bne[(size_t)k * 4 + t];
        bxek[t] = bxe[(size_t)k * 4 + t];
        wmnk[t] = wmn[(size_t)k * 4 + t];
        wmxk[t] = wmx[(size_t)k * 4 + t];
    }
    if (t == 0) cntS = 0;
    __syncthreads();
    const bool isBool = (*flag) != 0;
    int wave = t >> 6, lane = t & 63;
    uint32_t myCount = 0;
#pragma unroll
    for (int q = 0; q < 4; ++q) {
        int widx = q * 4 + wave;
        if (widx * 64 > k) continue;  // wave-uniform; unwritten words stay 0 in LDS
        int l = widx * 64 + lane;
        bool dA = false, dB = false, cand = false;
        if (l <= k) {
            if (isBool) {
                dA = disB[(size_t)k * KBOX + l] != 0;
                dB = disB[(size_t)l * KBOX + k] != 0;
            } else {
                const int* disI = (const int*)disB;
                dA = disI[(size_t)k * KBOX + l] != 0;
                dB = disI[(size_t)l * KBOX + k] != 0;
            }
            if (dA | dB) {
                float4 ml = *(const float4*)(wmn + (size_t)l * 4);
                float4 xl = *(const float4*)(wmx + (size_t)l * 4);
                cand = (ml.x <= wmxk[0]) & (wmnk[0] <= xl.x) &
                       (ml.y <= wmxk[1]) & (wmnk[1] <= xl.y) &
                       (ml.z <= wmxk[2]) & (wmnk[2] <= xl.z);
            }
        }
        bool bit = false;
        if (__ballot(cand ? 1 : 0)) {  // wave-uniform skip of heavy geometry
            if (cand) {
                const float* hl = hp + (size_t)l * 24;
                const float* bl = back + (size_t)l * 12;
                if (dA) {
                    bool rawA = false;
#pragma unroll
                    for (int c = 0; c < 8; ++c) {  // corners of l into frame k
                        float px = hl[c * 3 + 0], py = hl[c * 3 + 1], pz = hl[c * 3 + 2];
                        float x = bk[0] * px + bk[1] * py + bk[2] * pz + bk[3];
                        float y = bk[4] * px + bk[5] * py + bk[6] * pz + bk[7];
                        float z = bk[8] * px + bk[9] * py + bk[10] * pz + bk[11];
                        rawA = rawA || (x > bnek[0] && x < bxek[0] && y > bnek[1] &&
                                        y < bxek[1] && z > bnek[2] && z < bxek[2]);
                    }
                    bit = rawA;
                }
                if (dB && !bit) {
                    float4 bnl = *(const float4*)(bne + (size_t)l * 4);
                    float4 bxl = *(const float4*)(bxe + (size_t)l * 4);
                    bool rawB = false;
#pragma unroll
                    for (int c = 0; c < 8; ++c) {  // corners of k into frame l
                        float px = hk[c * 3 + 0], py = hk[c * 3 + 1], pz = hk[c * 3 + 2];
                        float x = bl[0] * px + bl[1] * py + bl[2] * pz + bl[3];
                        float y = bl[4] * px + bl[5] * py + bl[6] * pz + bl[7];
                        float z = bl[8] * px + bl[9] * py + bl[10] * pz + bl[11];
                        rawB = rawB || (x > bnl.x && x < bxl.x && y > bnl.y &&
                                        y < bxl.y && z > bnl.z && z < bxl.z);
                    }
                    bit = rawB;
                }
            }
        }
        uint64_t word = __ballot(bit ? 1 : 0);
        if (lane == 0) {
            words[widx] = word;
            if (word) atomicAdd(&cntS, (uint32_t)__popcll(word));
        }
    }
    __syncthreads();
    uint32_t cnt = cntS;
    // publish aggregate ASAP so successors can proceed
    if (t == 0)
        __hip_atomic_store(&pub[k], (1ull << 32) | (uint64_t)cnt,
                           __ATOMIC_RELEASE, __HIP_MEMORY_SCOPE_AGENT);
    if (t >= 64) return;  // wave 0 finishes the row

    // decoupled lookback: block k only waits on j < k (dispatched earlier, less work)
    uint32_t start = 0;
    if (t == 0) {
        uint32_t run = 0;
        int j = k - 1;
        while (j >= 0) {
            uint64_t v = __hip_atomic_load(&pub[j], __ATOMIC_ACQUIRE, __HIP_MEMORY_SCOPE_AGENT);
            uint32_t st = (uint32_t)(v >> 32);
            if (st == 0) continue;          // not yet published — spin
            run += (uint32_t)v;
            if (st == 2) break;             // inclusive prefix — done
            --j;                            // aggregate — keep walking back
        }
        start = run;
        __hip_atomic_store(&pub[k], (2ull << 32) | (uint64_t)(start + cnt),
                           __ATOMIC_RELEASE, __HIP_MEMORY_SCOPE_AGENT);
    }
    start = (uint32_t)__shfl((int)start, 0);

    uint64_t w = (t < 16) ? words[t] : 0ull;
    int c = (int)__popcll(w);
    int p = c;
#pragma unroll
    for (int off = 1; off < 64; off <<= 1) {
        int u = __shfl_up(p, off);
        if (t >= off) p += u;
    }
    int ofs = (int)start + (p - c);
    float fk = (float)k;
    while (w) {
        int b = __builtin_ctzll(w);
        int col = t * 64 + b;
        out[2 * (size_t)ofs + 0] = (float)col;  // min = col (tril => col <= row)
        out[2 * (size_t)ofs + 1] = fk;          // max = row
        ++ofs;
        w &= w - 1;
    }
}

extern "C" void kernel_launch(void* const* d_in, const int* in_sizes, int n_in,
                              void* d_out, int out_size, void* d_ws, size_t ws_size,
                              hipStream_t stream) {
    const float* bbmin = (const float*)d_in[0];
    const float* bbmax = (const float*)d_in[1];
    const float* A = (const float*)d_in[2];
    const uint8_t* dis = (const uint8_t*)d_in[3];
    float* out = (float*)d_out;

    char* ws = (char*)d_ws;
    int* flag = (int*)ws;
    float* back = (float*)(ws + BACK_OFF);
    float* hp = (float*)(ws + HP_OFF);
    float* wmn = (float*)(ws + WMN_OFF);
    float* wmx = (float*)(ws + WMX_OFF);
    float* bne = (float*)(ws + BNE_OFF);
    float* bxe = (float*)(ws + BXE_OFF);
    uint64_t* pub = (uint64_t*)(ws + PUB_OFF);

    k_prep<<<FILL_BLOCKS + 5, 256, 0, stream>>>(bbmin, bbmax, A, dis, flag, back, hp, out,
                                                wmn, wmx, bne, bxe, pub,
                                                (float4*)(out + KBOX * 24));
    k_inside_compact<<<KBOX, 256, 0, stream>>>(back, hp, wmn, wmx, bne, bxe, dis, flag,
                                               pub, out + KBOX * 24);
}

// Round 5
// 113.428 us; speedup vs baseline: 3.3816x; 3.3816x over previous
//
#include <hip/hip_runtime.h>
#include <stdint.h>

#define KBOX 1024
#define EPSF 1e-4f
#define SLACK 3e-5f
#define FILL_BLOCKS 2048  // 2048*256 float4 = 2*K*K floats

// ws layout (bytes):
//   0      : int flag  (1 = bool byte layout, 0 = int32 layout)
//   16     : back [K][12] f32  (48 KB)  rows of inverse affine (3x4)
//   49168  : hp   [K][24] f32  (96 KB)  posed corners xyz
//   147472 : wmn  [K][4] f32   (16 KB)  world AABB min (slack-expanded)
//   163856 : wmx  [K][4] f32   (16 KB)  world AABB max
//   180240 : bne  [K][4] f32   (16 KB)  bb_min + EPS
//   196624 : bxe  [K][4] f32   (16 KB)  bb_max - EPS
//   213008 : pub  [K] u64      (8 KB)   (1<<32)|count per row, cleared by k_prep
#define BACK_OFF 16
#define HP_OFF   49168
#define WMN_OFF  147472
#define WMX_OFF  163856
#define BNE_OFF  180240
#define BXE_OFF  196624
#define PUB_OFF  213008

__global__ void k_prep(const float* __restrict__ bbmin, const float* __restrict__ bbmax,
                       const float* __restrict__ A, const uint8_t* __restrict__ dis,
                       int* __restrict__ flag,
                       float* __restrict__ back, float* __restrict__ hp,
                       float* __restrict__ out_hposed,
                       float* __restrict__ wmn, float* __restrict__ wmx,
                       float* __restrict__ bne, float* __restrict__ bxe,
                       uint64_t* __restrict__ pub, float4* __restrict__ fillp) {
    int bid = blockIdx.x;
    int t = threadIdx.x;
    if (bid < FILL_BLOCKS) {
        fillp[bid * 256 + t] = make_float4(-1.f, -1.f, -1.f, -1.f);
        return;
    }
    if (bid < FILL_BLOCKS + 4) {
        int k = (bid - FILL_BLOCKS) * 256 + t;
        const float* a = A + (size_t)k * 16;
        float r[3][4];
#pragma unroll
        for (int i = 0; i < 3; ++i)
#pragma unroll
            for (int j = 0; j < 4; ++j) r[i][j] = a[i * 4 + j];

        // double-precision analytic inverse of the 3x3 block
        double m00 = r[0][0], m01 = r[0][1], m02 = r[0][2];
        double m10 = r[1][0], m11 = r[1][1], m12 = r[1][2];
        double m20 = r[2][0], m21 = r[2][1], m22 = r[2][2];
        double c00 = m11 * m22 - m12 * m21;
        double c01 = m12 * m20 - m10 * m22;
        double c02 = m10 * m21 - m11 * m20;
        double det = m00 * c00 + m01 * c01 + m02 * c02;
        double id = 1.0 / det;
        double inv[3][3];
        inv[0][0] = c00 * id;
        inv[0][1] = (m02 * m21 - m01 * m22) * id;
        inv[0][2] = (m01 * m12 - m02 * m11) * id;
        inv[1][0] = c01 * id;
        inv[1][1] = (m00 * m22 - m02 * m20) * id;
        inv[1][2] = (m02 * m10 - m00 * m12) * id;
        inv[2][0] = c02 * id;
        inv[2][1] = (m01 * m20 - m00 * m21) * id;
        inv[2][2] = (m00 * m11 - m01 * m10) * id;
        double tx = r[0][3], ty = r[1][3], tz = r[2][3];
#pragma unroll
        for (int i = 0; i < 3; ++i) {
            back[(size_t)k * 12 + i * 4 + 0] = (float)inv[i][0];
            back[(size_t)k * 12 + i * 4 + 1] = (float)inv[i][1];
            back[(size_t)k * 12 + i * 4 + 2] = (float)inv[i][2];
            back[(size_t)k * 12 + i * 4 + 3] =
                (float)(-(inv[i][0] * tx + inv[i][1] * ty + inv[i][2] * tz));
        }

        float bmn[3], bmx[3];
#pragma unroll
        for (int i = 0; i < 3; ++i) { bmn[i] = bbmin[k * 3 + i]; bmx[i] = bbmax[k * 3 + i]; }
        *(float4*)(bne + (size_t)k * 4) =
            make_float4(bmn[0] + EPSF, bmn[1] + EPSF, bmn[2] + EPSF, 0.f);
        *(float4*)(bxe + (size_t)k * 4) =
            make_float4(bmx[0] - EPSF, bmx[1] - EPSF, bmx[2] - EPSF, 0.f);

        float wn[3] = {1e30f, 1e30f, 1e30f}, wx[3] = {-1e30f, -1e30f, -1e30f};
#pragma unroll
        for (int c = 0; c < 8; ++c) {
            float cx = ((c >> 2) & 1) ? bmx[0] : bmn[0];
            float cy = ((c >> 1) & 1) ? bmx[1] : bmn[1];
            float cz = (c & 1) ? bmx[2] : bmn[2];
#pragma unroll
            for (int i = 0; i < 3; ++i) {
                float p = r[i][0] * cx + r[i][1] * cy + r[i][2] * cz + r[i][3];
                hp[(size_t)k * 24 + c * 3 + i] = p;
                out_hposed[(size_t)k * 24 + c * 3 + i] = p;
                wn[i] = fminf(wn[i], p);
                wx[i] = fmaxf(wx[i], p);
            }
        }
        *(float4*)(wmn + (size_t)k * 4) =
            make_float4(wn[0] - SLACK, wn[1] - SLACK, wn[2] - SLACK, 0.f);
        *(float4*)(wmx + (size_t)k * 4) =
            make_float4(wx[0] + SLACK, wx[1] + SLACK, wx[2] + SLACK, 0.f);
        return;
    }
    // last block: clear pub state (every replay) + detect dis layout
    for (int i = t; i < KBOX; i += 256) pub[i] = 0ull;
    __shared__ int s;
    if (t == 0) s = 0;
    __syncthreads();
    int acc = 0;
    for (int i = t; i < 4096; i += 256) {
        if ((i & 3) != 0 && dis[i] != 0) acc = 1;
    }
    if (acc) atomicOr(&s, 1);
    __syncthreads();
    if (t == 0) *flag = s;
}

__global__ void k_inside_compact(const float* __restrict__ back, const float* __restrict__ hp,
                                 const float* __restrict__ wmn, const float* __restrict__ wmx,
                                 const float* __restrict__ bne, const float* __restrict__ bxe,
                                 const uint8_t* __restrict__ disB, const int* __restrict__ flag,
                                 uint64_t* __restrict__ pub, float* __restrict__ out) {
    int k = blockIdx.x;
    __shared__ float bk[12], hk[24], bnek[3], bxek[3], wmnk[3], wmxk[3];
    __shared__ uint64_t words[16];
    __shared__ uint32_t cntS;
    int t = threadIdx.x;
    if (t < 16) words[t] = 0ull;
    if (t < 12) bk[t] = back[(size_t)k * 12 + t];
    if (t < 24) hk[t] = hp[(size_t)k * 24 + t];
    if (t < 3) {
        bnek[t] = bne[(size_t)k * 4 + t];
        bxek[t] = bxe[(size_t)k * 4 + t];
        wmnk[t] = wmn[(size_t)k * 4 + t];
        wmxk[t] = wmx[(size_t)k * 4 + t];
    }
    if (t == 0) cntS = 0;
    __syncthreads();
    const bool isBool = (*flag) != 0;
    int wave = t >> 6, lane = t & 63;
#pragma unroll
    for (int q = 0; q < 4; ++q) {
        int widx = q * 4 + wave;
        if (widx * 64 > k) continue;  // wave-uniform; unwritten words stay 0 in LDS
        int l = widx * 64 + lane;
        bool dA = false, dB = false, cand = false;
        if (l <= k) {
            if (isBool) {
                dA = disB[(size_t)k * KBOX + l] != 0;
                dB = disB[(size_t)l * KBOX + k] != 0;
            } else {
                const int* disI = (const int*)disB;
                dA = disI[(size_t)k * KBOX + l] != 0;
                dB = disI[(size_t)l * KBOX + k] != 0;
            }
            if (dA | dB) {
                float4 ml = *(const float4*)(wmn + (size_t)l * 4);
                float4 xl = *(const float4*)(wmx + (size_t)l * 4);
                cand = (ml.x <= wmxk[0]) & (wmnk[0] <= xl.x) &
                       (ml.y <= wmxk[1]) & (wmnk[1] <= xl.y) &
                       (ml.z <= wmxk[2]) & (wmnk[2] <= xl.z);
            }
        }
        bool bit = false;
        if (__ballot(cand ? 1 : 0)) {  // wave-uniform skip of heavy geometry
            if (cand) {
                const float* hl = hp + (size_t)l * 24;
                const float* bl = back + (size_t)l * 12;
                if (dA) {
                    bool rawA = false;
#pragma unroll
                    for (int c = 0; c < 8; ++c) {  // corners of l into frame k
                        float px = hl[c * 3 + 0], py = hl[c * 3 + 1], pz = hl[c * 3 + 2];
                        float x = bk[0] * px + bk[1] * py + bk[2] * pz + bk[3];
                        float y = bk[4] * px + bk[5] * py + bk[6] * pz + bk[7];
                        float z = bk[8] * px + bk[9] * py + bk[10] * pz + bk[11];
                        rawA = rawA || (x > bnek[0] && x < bxek[0] && y > bnek[1] &&
                                        y < bxek[1] && z > bnek[2] && z < bxek[2]);
                    }
                    bit = rawA;
                }
                if (dB && !bit) {
                    float4 bnl = *(const float4*)(bne + (size_t)l * 4);
                    float4 bxl = *(const float4*)(bxe + (size_t)l * 4);
                    bool rawB = false;
#pragma unroll
                    for (int c = 0; c < 8; ++c) {  // corners of k into frame l
                        float px = hk[c * 3 + 0], py = hk[c * 3 + 1], pz = hk[c * 3 + 2];
                        float x = bl[0] * px + bl[1] * py + bl[2] * pz + bl[3];
                        float y = bl[4] * px + bl[5] * py + bl[6] * pz + bl[7];
                        float z = bl[8] * px + bl[9] * py + bl[10] * pz + bl[11];
                        rawB = rawB || (x > bnl.x && x < bxl.x && y > bnl.y &&
                                        y < bxl.y && z > bnl.z && z < bxl.z);
                    }
                    bit = rawB;
                }
            }
        }
        uint64_t word = __ballot(bit ? 1 : 0);
        if (lane == 0) {
            words[widx] = word;
            if (word) atomicAdd(&cntS, (uint32_t)__popcll(word));
        }
    }
    __syncthreads();
    uint32_t cnt = cntS;
    // publish this row's aggregate immediately (pub pre-cleared by k_prep)
    if (t == 0)
        __hip_atomic_store(&pub[k], (1ull << 32) | (uint64_t)cnt,
                           __ATOMIC_RELEASE, __HIP_MEMORY_SCOPE_AGENT);
    if (t >= 64) return;  // wave 0 finishes the row

    // start[k] = sum of aggregates of all j<k — 64 lanes in parallel, coalesced.
    // No prefix chain: every block publishes its aggregate right after ~2us of
    // compute, so <=16 parallel load rounds suffice (round-4 serial walk: 382us).
    uint32_t s = 0;
    for (int idx = t; idx < k; idx += 64) {
        uint64_t v = __hip_atomic_load(&pub[idx], __ATOMIC_ACQUIRE, __HIP_MEMORY_SCOPE_AGENT);
        while ((v >> 32) == 0) {  // rare: predecessor not yet published
            __builtin_amdgcn_s_sleep(8);
            v = __hip_atomic_load(&pub[idx], __ATOMIC_ACQUIRE, __HIP_MEMORY_SCOPE_AGENT);
        }
        s += (uint32_t)v;
    }
#pragma unroll
    for (int off = 32; off > 0; off >>= 1) s += __shfl_xor(s, off);
    uint32_t start = s;  // uniform across wave

    uint64_t w = (t < 16) ? words[t] : 0ull;
    int c = (int)__popcll(w);
    int p = c;
#pragma unroll
    for (int off = 1; off < 64; off <<= 1) {
        int u = __shfl_up(p, off);
        if (t >= off) p += u;
    }
    int ofs = (int)start + (p - c);
    float fk = (float)k;
    while (w) {
        int b = __builtin_ctzll(w);
        int col = t * 64 + b;
        out[2 * (size_t)ofs + 0] = (float)col;  // min = col (tril => col <= row)
        out[2 * (size_t)ofs + 1] = fk;          // max = row
        ++ofs;
        w &= w - 1;
    }
}

extern "C" void kernel_launch(void* const* d_in, const int* in_sizes, int n_in,
                              void* d_out, int out_size, void* d_ws, size_t ws_size,
                              hipStream_t stream) {
    const float* bbmin = (const float*)d_in[0];
    const float* bbmax = (const float*)d_in[1];
    const float* A = (const float*)d_in[2];
    const uint8_t* dis = (const uint8_t*)d_in[3];
    float* out = (float*)d_out;

    char* ws = (char*)d_ws;
    int* flag = (int*)ws;
    float* back = (float*)(ws + BACK_OFF);
    float* hp = (float*)(ws + HP_OFF);
    float* wmn = (float*)(ws + WMN_OFF);
    float* wmx = (float*)(ws + WMX_OFF);
    float* bne = (float*)(ws + BNE_OFF);
    float* bxe = (float*)(ws + BXE_OFF);
    uint64_t* pub = (uint64_t*)(ws + PUB_OFF);

    k_prep<<<FILL_BLOCKS + 5, 256, 0, stream>>>(bbmin, bbmax, A, dis, flag, back, hp, out,
                                                wmn, wmx, bne, bxe, pub,
                                                (float4*)(out + KBOX * 24));
    k_inside_compact<<<KBOX, 256, 0, stream>>>(back, hp, wmn, wmx, bne, bxe, dis, flag,
                                               pub, out + KBOX * 24);
}

// Round 6
// 28.052 us; speedup vs baseline: 13.6731x; 4.0434x over previous
//
#include <hip/hip_runtime.h>
#include <stdint.h>

#define KBOX 1024
#define EPSF 1e-4f
#define SLACK 3e-5f
#define FILL_BLOCKS 2048  // 2048*256 float4 = 2*K*K floats

// ws layout (bytes):
//   0      : int flag  (1 = bool byte layout, 0 = int32 layout)
//   16     : back [K][12] f32  (48 KB)  rows of inverse affine (3x4)
//   49168  : hp   [K][24] f32  (96 KB)  posed corners xyz
//   147472 : wmn  [K][4] f32   (16 KB)  world AABB min (slack-expanded)
//   163856 : wmx  [K][4] f32   (16 KB)  world AABB max
//   180240 : bne  [K][4] f32   (16 KB)  bb_min + EPS
//   196624 : bxe  [K][4] f32   (16 KB)  bb_max - EPS
//   213008 : bm   [K][16] u64  (128 KB) inside bitmask words
//   344080 : tileCnt [4096] u32 (16 KB) per (row,tile) count
#define BACK_OFF 16
#define HP_OFF   49168
#define WMN_OFF  147472
#define WMX_OFF  163856
#define BNE_OFF  180240
#define BXE_OFF  196624
#define BM_OFF   213008
#define TC_OFF   344080

__global__ void k_prep(const float* __restrict__ bbmin, const float* __restrict__ bbmax,
                       const float* __restrict__ A, const uint8_t* __restrict__ dis,
                       int* __restrict__ flag,
                       float* __restrict__ back, float* __restrict__ hp,
                       float* __restrict__ out_hposed,
                       float* __restrict__ wmn, float* __restrict__ wmx,
                       float* __restrict__ bne, float* __restrict__ bxe,
                       float4* __restrict__ fillp) {
    int bid = blockIdx.x;
    int t = threadIdx.x;
    if (bid < FILL_BLOCKS) {
        fillp[bid * 256 + t] = make_float4(-1.f, -1.f, -1.f, -1.f);
        return;
    }
    if (bid < FILL_BLOCKS + 4) {
        int k = (bid - FILL_BLOCKS) * 256 + t;
        const float* a = A + (size_t)k * 16;
        float r[3][4];
#pragma unroll
        for (int i = 0; i < 3; ++i)
#pragma unroll
            for (int j = 0; j < 4; ++j) r[i][j] = a[i * 4 + j];

        // double-precision analytic inverse of the 3x3 block
        double m00 = r[0][0], m01 = r[0][1], m02 = r[0][2];
        double m10 = r[1][0], m11 = r[1][1], m12 = r[1][2];
        double m20 = r[2][0], m21 = r[2][1], m22 = r[2][2];
        double c00 = m11 * m22 - m12 * m21;
        double c01 = m12 * m20 - m10 * m22;
        double c02 = m10 * m21 - m11 * m20;
        double det = m00 * c00 + m01 * c01 + m02 * c02;
        double id = 1.0 / det;
        double inv[3][3];
        inv[0][0] = c00 * id;
        inv[0][1] = (m02 * m21 - m01 * m22) * id;
        inv[0][2] = (m01 * m12 - m02 * m11) * id;
        inv[1][0] = c01 * id;
        inv[1][1] = (m00 * m22 - m02 * m20) * id;
        inv[1][2] = (m02 * m10 - m00 * m12) * id;
        inv[2][0] = c02 * id;
        inv[2][1] = (m01 * m20 - m00 * m21) * id;
        inv[2][2] = (m00 * m11 - m01 * m10) * id;
        double tx = r[0][3], ty = r[1][3], tz = r[2][3];
#pragma unroll
        for (int i = 0; i < 3; ++i) {
            back[(size_t)k * 12 + i * 4 + 0] = (float)inv[i][0];
            back[(size_t)k * 12 + i * 4 + 1] = (float)inv[i][1];
            back[(size_t)k * 12 + i * 4 + 2] = (float)inv[i][2];
            back[(size_t)k * 12 + i * 4 + 3] =
                (float)(-(inv[i][0] * tx + inv[i][1] * ty + inv[i][2] * tz));
        }

        float bmn[3], bmx[3];
#pragma unroll
        for (int i = 0; i < 3; ++i) { bmn[i] = bbmin[k * 3 + i]; bmx[i] = bbmax[k * 3 + i]; }
        *(float4*)(bne + (size_t)k * 4) =
            make_float4(bmn[0] + EPSF, bmn[1] + EPSF, bmn[2] + EPSF, 0.f);
        *(float4*)(bxe + (size_t)k * 4) =
            make_float4(bmx[0] - EPSF, bmx[1] - EPSF, bmx[2] - EPSF, 0.f);

        float wn[3] = {1e30f, 1e30f, 1e30f}, wx[3] = {-1e30f, -1e30f, -1e30f};
#pragma unroll
        for (int c = 0; c < 8; ++c) {
            float cx = ((c >> 2) & 1) ? bmx[0] : bmn[0];
            float cy = ((c >> 1) & 1) ? bmx[1] : bmn[1];
            float cz = (c & 1) ? bmx[2] : bmn[2];
#pragma unroll
            for (int i = 0; i < 3; ++i) {
                float p = r[i][0] * cx + r[i][1] * cy + r[i][2] * cz + r[i][3];
                hp[(size_t)k * 24 + c * 3 + i] = p;
                out_hposed[(size_t)k * 24 + c * 3 + i] = p;
                wn[i] = fminf(wn[i], p);
                wx[i] = fmaxf(wx[i], p);
            }
        }
        *(float4*)(wmn + (size_t)k * 4) =
            make_float4(wn[0] - SLACK, wn[1] - SLACK, wn[2] - SLACK, 0.f);
        *(float4*)(wmx + (size_t)k * 4) =
            make_float4(wx[0] + SLACK, wx[1] + SLACK, wx[2] + SLACK, 0.f);
        return;
    }
    // last block: detect dis layout (bool bytes vs int32)
    __shared__ int s;
    if (t == 0) s = 0;
    __syncthreads();
    int acc = 0;
    for (int i = t; i < 4096; i += 256) {
        if ((i & 3) != 0 && dis[i] != 0) acc = 1;
    }
    if (acc) atomicOr(&s, 1);
    __syncthreads();
    if (t == 0) *flag = s;
}

// One block per (row k, 256-col tile j): a single latency-chain iteration per
// block (round-3's row-per-block version serialized up to 16 of these chains).
__global__ void k_inside(const float* __restrict__ back, const float* __restrict__ hp,
                         const float* __restrict__ wmn, const float* __restrict__ wmx,
                         const float* __restrict__ bne, const float* __restrict__ bxe,
                         const uint8_t* __restrict__ disB, const int* __restrict__ flag,
                         uint64_t* __restrict__ bm, uint32_t* __restrict__ tileCnt) {
    int bid = blockIdx.x;
    int k = bid >> 2, j = bid & 3;
    int t = threadIdx.x;
    if (j * 256 > k) {  // whole tile above diagonal: publish 0 (read-set = write-set)
        if (t == 0) tileCnt[bid] = 0;
        return;
    }
    __shared__ float bk[12], hk[24], bnek[3], bxek[3], wmnk[3], wmxk[3];
    __shared__ uint32_t cntS;
    if (t < 12) bk[t] = back[(size_t)k * 12 + t];
    if (t < 24) hk[t] = hp[(size_t)k * 24 + t];
    if (t < 3) {
        bnek[t] = bne[(size_t)k * 4 + t];
        bxek[t] = bxe[(size_t)k * 4 + t];
        wmnk[t] = wmn[(size_t)k * 4 + t];
        wmxk[t] = wmx[(size_t)k * 4 + t];
    }
    if (t == 0) cntS = 0;
    __syncthreads();
    const bool isBool = (*flag) != 0;
    int wave = t >> 6, lane = t & 63;
    int widx = j * 4 + wave;
    if (widx * 64 <= k) {  // wave-uniform
        int l = widx * 64 + lane;
        bool dA = false, dB = false, cand = false;
        if (l <= k) {
            if (isBool) {
                dA = disB[(size_t)k * KBOX + l] != 0;
                dB = disB[(size_t)l * KBOX + k] != 0;
            } else {
                const int* disI = (const int*)disB;
                dA = disI[(size_t)k * KBOX + l] != 0;
                dB = disI[(size_t)l * KBOX + k] != 0;
            }
            if (dA | dB) {
                float4 ml = *(const float4*)(wmn + (size_t)l * 4);
                float4 xl = *(const float4*)(wmx + (size_t)l * 4);
                cand = (ml.x <= wmxk[0]) & (wmnk[0] <= xl.x) &
                       (ml.y <= wmxk[1]) & (wmnk[1] <= xl.y) &
                       (ml.z <= wmxk[2]) & (wmnk[2] <= xl.z);
            }
        }
        bool bit = false;
        if (__ballot(cand ? 1 : 0)) {  // wave-uniform skip of heavy geometry
            if (cand) {
                const float* hl = hp + (size_t)l * 24;
                const float* bl = back + (size_t)l * 12;
                if (dA) {
                    bool rawA = false;
#pragma unroll
                    for (int c = 0; c < 8; ++c) {  // corners of l into frame k
                        float px = hl[c * 3 + 0], py = hl[c * 3 + 1], pz = hl[c * 3 + 2];
                        float x = bk[0] * px + bk[1] * py + bk[2] * pz + bk[3];
                        float y = bk[4] * px + bk[5] * py + bk[6] * pz + bk[7];
                        float z = bk[8] * px + bk[9] * py + bk[10] * pz + bk[11];
                        rawA = rawA || (x > bnek[0] && x < bxek[0] && y > bnek[1] &&
                                        y < bxek[1] && z > bnek[2] && z < bxek[2]);
                    }
                    bit = rawA;
                }
                if (dB && !bit) {
                    float4 bnl = *(const float4*)(bne + (size_t)l * 4);
                    float4 bxl = *(const float4*)(bxe + (size_t)l * 4);
                    bool rawB = false;
#pragma unroll
                    for (int c = 0; c < 8; ++c) {  // corners of k into frame l
                        float px = hk[c * 3 + 0], py = hk[c * 3 + 1], pz = hk[c * 3 + 2];
                        float x = bl[0] * px + bl[1] * py + bl[2] * pz + bl[3];
                        float y = bl[4] * px + bl[5] * py + bl[6] * pz + bl[7];
                        float z = bl[8] * px + bl[9] * py + bl[10] * pz + bl[11];
                        rawB = rawB || (x > bnl.x && x < bxl.x && y > bnl.y &&
                                        y < bxl.y && z > bnl.z && z < bxl.z);
                    }
                    bit = rawB;
                }
            }
        }
        uint64_t word = __ballot(bit ? 1 : 0);
        if (lane == 0) {
            bm[(size_t)k * 16 + widx] = word;
            if (word) atomicAdd(&cntS, (uint32_t)__popcll(word));
        }
    }
    __syncthreads();
    if (t == 0) tileCnt[bid] = cntS;
}

__global__ void k_compact(const uint64_t* __restrict__ bm,
                          const uint32_t* __restrict__ tileCnt, float* __restrict__ out) {
    int k = blockIdx.x;
    int t = threadIdx.x;  // 256 threads
    int wave = t >> 6, lane = t & 63;
    __shared__ uint32_t ws4[4];
    // start = sum of all tile counts before row k (tiles are row-contiguous)
    uint32_t s = 0;
    for (int idx = t; idx < 4 * k; idx += 256) s += tileCnt[idx];
#pragma unroll
    for (int off = 32; off > 0; off >>= 1) s += __shfl_xor(s, off);
    if (lane == 0) ws4[wave] = s;
    __syncthreads();
    if (t >= 64) return;  // wave 0 finishes the row
    uint32_t start = ws4[0] + ws4[1] + ws4[2] + ws4[3];

    // only words with t*64 <= k are written by k_inside; mask the rest
    uint64_t w = (t < 16 && t * 64 <= k) ? bm[(size_t)k * 16 + t] : 0ull;
    int c = (int)__popcll(w);
    int p = c;
#pragma unroll
    for (int off = 1; off < 64; off <<= 1) {
        int u = __shfl_up(p, off);
        if (t >= off) p += u;
    }
    int ofs = (int)start + (p - c);
    float fk = (float)k;
    while (w) {
        int b = __builtin_ctzll(w);
        int col = t * 64 + b;
        out[2 * (size_t)ofs + 0] = (float)col;  // min = col (tril => col <= row)
        out[2 * (size_t)ofs + 1] = fk;          // max = row
        ++ofs;
        w &= w - 1;
    }
}

extern "C" void kernel_launch(void* const* d_in, const int* in_sizes, int n_in,
                              void* d_out, int out_size, void* d_ws, size_t ws_size,
                              hipStream_t stream) {
    const float* bbmin = (const float*)d_in[0];
    const float* bbmax = (const float*)d_in[1];
    const float* A = (const float*)d_in[2];
    const uint8_t* dis = (const uint8_t*)d_in[3];
    float* out = (float*)d_out;

    char* ws = (char*)d_ws;
    int* flag = (int*)ws;
    float* back = (float*)(ws + BACK_OFF);
    float* hp = (float*)(ws + HP_OFF);
    float* wmn = (float*)(ws + WMN_OFF);
    float* wmx = (float*)(ws + WMX_OFF);
    float* bne = (float*)(ws + BNE_OFF);
    float* bxe = (float*)(ws + BXE_OFF);
    uint64_t* bm = (uint64_t*)(ws + BM_OFF);
    uint32_t* tileCnt = (uint32_t*)(ws + TC_OFF);

    k_prep<<<FILL_BLOCKS + 5, 256, 0, stream>>>(bbmin, bbmax, A, dis, flag, back, hp, out,
                                                wmn, wmx, bne, bxe,
                                                (float4*)(out + KBOX * 24));
    k_inside<<<KBOX * 4, 256, 0, stream>>>(back, hp, wmn, wmx, bne, bxe, dis, flag,
                                           bm, tileCnt);
    k_compact<<<KBOX, 256, 0, stream>>>(bm, tileCnt, out + KBOX * 24);
}

// Round 7
// 24.687 us; speedup vs baseline: 15.5370x; 1.1363x over previous
//
#include <hip/hip_runtime.h>
#include <stdint.h>

#define KBOX 1024
#define EPSF 1e-4f
#define SLACK 3e-5f
#define TILE_BLOCKS 4096   // 1024 rows x 4 col-tiles (256 cols each)
#define FILL_BLOCKS 2048   // 2048*256 float4 = 2*K*K floats
#define POSE_BLOCKS 4      // 4*256 = 1024 boxes -> hposed output

// ws layout (bytes):
//   0      : bm [K][16] u64   (128 KB) inside bitmask words
//   131072 : tileCnt [4096] u32 (16 KB) per (row,tile) count
#define BM_OFF 0
#define TC_OFF 131072

// double-precision analytic inverse of the affine 3x4 (rows of A), -> 12 floats
__device__ inline void inv_affine(const float r[12], float o[12]) {
    double m00 = r[0], m01 = r[1], m02 = r[2];
    double m10 = r[4], m11 = r[5], m12 = r[6];
    double m20 = r[8], m21 = r[9], m22 = r[10];
    double c00 = m11 * m22 - m12 * m21;
    double c01 = m12 * m20 - m10 * m22;
    double c02 = m10 * m21 - m11 * m20;
    double det = m00 * c00 + m01 * c01 + m02 * c02;
    double id = 1.0 / det;
    double i00 = c00 * id, i01 = (m02 * m21 - m01 * m22) * id, i02 = (m01 * m12 - m02 * m11) * id;
    double i10 = c01 * id, i11 = (m00 * m22 - m02 * m20) * id, i12 = (m02 * m10 - m00 * m12) * id;
    double i20 = c02 * id, i21 = (m01 * m20 - m00 * m21) * id, i22 = (m00 * m11 - m01 * m10) * id;
    double tx = r[3], ty = r[7], tz = r[11];
    o[0] = (float)i00; o[1] = (float)i01; o[2] = (float)i02;
    o[3] = (float)(-(i00 * tx + i01 * ty + i02 * tz));
    o[4] = (float)i10; o[5] = (float)i11; o[6] = (float)i12;
    o[7] = (float)(-(i10 * tx + i11 * ty + i12 * tz));
    o[8] = (float)i20; o[9] = (float)i21; o[10] = (float)i22;
    o[11] = (float)(-(i20 * tx + i21 * ty + i22 * tz));
}

__global__ void k_main(const float* __restrict__ bbmin, const float* __restrict__ bbmax,
                       const float* __restrict__ A, const uint8_t* __restrict__ disB,
                       float* __restrict__ out_hposed, float4* __restrict__ fillp,
                       uint64_t* __restrict__ bm, uint32_t* __restrict__ tileCnt) {
    int bid = blockIdx.x;
    int t = threadIdx.x;

    if (bid >= TILE_BLOCKS) {
        int b2 = bid - TILE_BLOCKS;
        if (b2 < FILL_BLOCKS) {  // -1 fill of the index region
            fillp[b2 * 256 + t] = make_float4(-1.f, -1.f, -1.f, -1.f);
            return;
        }
        // pose-output blocks: write hposed[...,:3] (output 0)
        int k = (b2 - FILL_BLOCKS) * 256 + t;
        float r[12];
#pragma unroll
        for (int i = 0; i < 12; ++i) r[i] = A[(size_t)k * 16 + i];
        float bmn[3], bmx[3];
#pragma unroll
        for (int i = 0; i < 3; ++i) { bmn[i] = bbmin[k * 3 + i]; bmx[i] = bbmax[k * 3 + i]; }
#pragma unroll
        for (int c = 0; c < 8; ++c) {
            float cx = ((c >> 2) & 1) ? bmx[0] : bmn[0];
            float cy = ((c >> 1) & 1) ? bmx[1] : bmn[1];
            float cz = (c & 1) ? bmx[2] : bmn[2];
#pragma unroll
            for (int i = 0; i < 3; ++i)
                out_hposed[(size_t)k * 24 + c * 3 + i] =
                    r[i * 4 + 0] * cx + r[i * 4 + 1] * cy + r[i * 4 + 2] * cz + r[i * 4 + 3];
        }
        return;
    }

    // ---- tile block: row k, cols j*256 .. j*256+255, self-contained ----
    int k = bid >> 2, j = bid & 3;
    if (j * 256 > k) {  // fully above diagonal
        if (t == 0) tileCnt[bid] = 0;
        return;
    }
    __shared__ float bk[12], hk[24];
    __shared__ float bnek[3], bxek[3], wmnk[3], wmxk[3];
    __shared__ int flagS;
    __shared__ uint32_t cntS;

    // dis layout detection from first 1 KB (int32 0/1 data has all non-aligned
    // bytes zero; random bools don't — false-negative prob ~2^-768)
    uint32_t dw = ((const uint32_t*)disB)[t];
    bool nzb = (dw & 0xFFFFFF00u) != 0;
    if (t == 0) { flagS = 0; cntS = 0; }
    __syncthreads();
    if (nzb) atomicOr(&flagS, 1);

    // thread 0: row-k pose data into LDS (same fp64 formula everywhere -> deterministic)
    if (t == 0) {
        float rk[12];
#pragma unroll
        for (int i = 0; i < 12; ++i) rk[i] = A[(size_t)k * 16 + i];
        inv_affine(rk, bk);
        float bmn[3], bmx[3];
#pragma unroll
        for (int i = 0; i < 3; ++i) { bmn[i] = bbmin[k * 3 + i]; bmx[i] = bbmax[k * 3 + i]; }
#pragma unroll
        for (int i = 0; i < 3; ++i) { bnek[i] = bmn[i] + EPSF; bxek[i] = bmx[i] - EPSF; }
        float wn[3] = {1e30f, 1e30f, 1e30f}, wx[3] = {-1e30f, -1e30f, -1e30f};
#pragma unroll
        for (int c = 0; c < 8; ++c) {
            float cx = ((c >> 2) & 1) ? bmx[0] : bmn[0];
            float cy = ((c >> 1) & 1) ? bmx[1] : bmn[1];
            float cz = (c & 1) ? bmx[2] : bmn[2];
#pragma unroll
            for (int i = 0; i < 3; ++i) {
                float p = rk[i * 4 + 0] * cx + rk[i * 4 + 1] * cy + rk[i * 4 + 2] * cz + rk[i * 4 + 3];
                hk[c * 3 + i] = p;
                wn[i] = fminf(wn[i], p);
                wx[i] = fmaxf(wx[i], p);
            }
        }
#pragma unroll
        for (int i = 0; i < 3; ++i) { wmnk[i] = wn[i] - SLACK; wmxk[i] = wx[i] + SLACK; }
    }

    // every thread: col box l — corners + world AABB (registers only)
    int l = j * 256 + t;
    float rl[12];
#pragma unroll
    for (int i = 0; i < 3; ++i) {
        float4 a4 = *(const float4*)(A + (size_t)l * 16 + i * 4);
        rl[i * 4 + 0] = a4.x; rl[i * 4 + 1] = a4.y; rl[i * 4 + 2] = a4.z; rl[i * 4 + 3] = a4.w;
    }
    float bmnl[3], bmxl[3];
#pragma unroll
    for (int i = 0; i < 3; ++i) { bmnl[i] = bbmin[l * 3 + i]; bmxl[i] = bbmax[l * 3 + i]; }
    float hl[24];
    float wnl[3] = {1e30f, 1e30f, 1e30f}, wxl[3] = {-1e30f, -1e30f, -1e30f};
#pragma unroll
    for (int c = 0; c < 8; ++c) {
        float cx = ((c >> 2) & 1) ? bmxl[0] : bmnl[0];
        float cy = ((c >> 1) & 1) ? bmxl[1] : bmnl[1];
        float cz = (c & 1) ? bmxl[2] : bmnl[2];
#pragma unroll
        for (int i = 0; i < 3; ++i) {
            float p = rl[i * 4 + 0] * cx + rl[i * 4 + 1] * cy + rl[i * 4 + 2] * cz + rl[i * 4 + 3];
            hl[c * 3 + i] = p;
            wnl[i] = fminf(wnl[i], p);
            wxl[i] = fmaxf(wxl[i], p);
        }
    }
    __syncthreads();
    const bool isBool = flagS != 0;

    // AABB candidate gate FIRST (hot data); dis bits loaded only for candidates
    bool cand = false;
    if (l <= k) {
        cand = (wnl[0] - SLACK <= wmxk[0]) & (wmnk[0] <= wxl[0] + SLACK) &
               (wnl[1] - SLACK <= wmxk[1]) & (wmnk[1] <= wxl[1] + SLACK) &
               (wnl[2] - SLACK <= wmxk[2]) & (wmnk[2] <= wxl[2] + SLACK);
    }
    bool bit = false;
    if (__ballot(cand ? 1 : 0)) {
        bool dA = false, dB = false;
        if (cand) {
            if (isBool) {
                dA = disB[(size_t)k * KBOX + l] != 0;
                dB = disB[(size_t)l * KBOX + k] != 0;
            } else {
                const int* disI = (const int*)disB;
                dA = disI[(size_t)k * KBOX + l] != 0;
                dB = disI[(size_t)l * KBOX + k] != 0;
            }
        }
        if (cand && dA) {  // corners of l into frame k
            bool rawA = false;
#pragma unroll
            for (int c = 0; c < 8; ++c) {
                float px = hl[c * 3 + 0], py = hl[c * 3 + 1], pz = hl[c * 3 + 2];
                float x = bk[0] * px + bk[1] * py + bk[2] * pz + bk[3];
                float y = bk[4] * px + bk[5] * py + bk[6] * pz + bk[7];
                float z = bk[8] * px + bk[9] * py + bk[10] * pz + bk[11];
                rawA = rawA || (x > bnek[0] && x < bxek[0] && y > bnek[1] && y < bxek[1] &&
                                z > bnek[2] && z < bxek[2]);
            }
            bit = rawA;
        }
        if (cand && dB && !bit) {  // corners of k into frame l (inverse computed on demand)
            float bl[12];
            inv_affine(rl, bl);
            float bnl[3], bxl[3];
#pragma unroll
            for (int i = 0; i < 3; ++i) { bnl[i] = bmnl[i] + EPSF; bxl[i] = bmxl[i] - EPSF; }
            bool rawB = false;
#pragma unroll
            for (int c = 0; c < 8; ++c) {
                float px = hk[c * 3 + 0], py = hk[c * 3 + 1], pz = hk[c * 3 + 2];
                float x = bl[0] * px + bl[1] * py + bl[2] * pz + bl[3];
                float y = bl[4] * px + bl[5] * py + bl[6] * pz + bl[7];
                float z = bl[8] * px + bl[9] * py + bl[10] * pz + bl[11];
                rawB = rawB || (x > bnl[0] && x < bxl[0] && y > bnl[1] && y < bxl[1] &&
                                z > bnl[2] && z < bxl[2]);
            }
            bit = rawB;
        }
    }
    uint64_t word = __ballot(bit ? 1 : 0);
    int lane = t & 63, wave = t >> 6;
    if (lane == 0) {
        bm[(size_t)k * 16 + j * 4 + wave] = word;  // zero words above diag are fine
        if (word) atomicAdd(&cntS, (uint32_t)__popcll(word));
    }
    __syncthreads();
    if (t == 0) tileCnt[bid] = cntS;
}

__global__ void k_compact(const uint64_t* __restrict__ bm,
                          const uint32_t* __restrict__ tileCnt, float* __restrict__ out) {
    int k = blockIdx.x;
    int t = threadIdx.x;  // 256 threads
    int wave = t >> 6, lane = t & 63;
    __shared__ uint32_t ws4[4];
    // start = sum of all tile counts before row k (tiles are row-contiguous)
    uint32_t s = 0;
    for (int idx = t; idx < 4 * k; idx += 256) s += tileCnt[idx];
#pragma unroll
    for (int off = 32; off > 0; off >>= 1) s += __shfl_xor(s, off);
    if (lane == 0) ws4[wave] = s;
    __syncthreads();
    if (t >= 64) return;  // wave 0 finishes the row
    uint32_t start = ws4[0] + ws4[1] + ws4[2] + ws4[3];

    // only words with t*64 <= k are meaningful; mask the rest
    uint64_t w = (t < 16 && t * 64 <= k) ? bm[(size_t)k * 16 + t] : 0ull;
    int c = (int)__popcll(w);
    int p = c;
#pragma unroll
    for (int off = 1; off < 64; off <<= 1) {
        int u = __shfl_up(p, off);
        if (t >= off) p += u;
    }
    int ofs = (int)start + (p - c);
    float fk = (float)k;
    while (w) {
        int b = __builtin_ctzll(w);
        int col = t * 64 + b;
        out[2 * (size_t)ofs + 0] = (float)col;  // min = col (tril => col <= row)
        out[2 * (size_t)ofs + 1] = fk;          // max = row
        ++ofs;
        w &= w - 1;
    }
}

extern "C" void kernel_launch(void* const* d_in, const int* in_sizes, int n_in,
                              void* d_out, int out_size, void* d_ws, size_t ws_size,
                              hipStream_t stream) {
    const float* bbmin = (const float*)d_in[0];
    const float* bbmax = (const float*)d_in[1];
    const float* A = (const float*)d_in[2];
    const uint8_t* dis = (const uint8_t*)d_in[3];
    float* out = (float*)d_out;

    char* ws = (char*)d_ws;
    uint64_t* bm = (uint64_t*)(ws + BM_OFF);
    uint32_t* tileCnt = (uint32_t*)(ws + TC_OFF);

    k_main<<<TILE_BLOCKS + FILL_BLOCKS + POSE_BLOCKS, 256, 0, stream>>>(
        bbmin, bbmax, A, dis, out, (float4*)(out + KBOX * 24), bm, tileCnt);
    k_compact<<<KBOX, 256, 0, stream>>>(bm, tileCnt, out + KBOX * 24);
}